// Round 14
// baseline (899.673 us; speedup 1.0000x reference)
//
#include <hip/hip_runtime.h>
#include <hip/hip_cooperative_groups.h>

namespace cg = cooperative_groups;

// SparseLoRAMoE — ONE cooperative kernel (3 phases, 2 grid.sync()).
// r13 audit: harness floor ~66-72us (fills+memsets), our 3 kernels ~55-60us,
// but all invisible below the 42us fill line in top-5 -> 6 rounds of blind
// neutral results. This round restores OBSERVABILITY: single dispatch that
// must appear in top-5 with counters, plus kills 2 launch gaps and k1's
// separate dispatch.
//   Grid 2048 x 128thr, (128,4): <=128 VGPR, ~9KB LDS -> exactly 8 blocks/CU
//   co-resident (VGPR-limited), 4 waves/SIMD.
//   P1: blocks 0-15 expert buckets, 16-271 pair buckets (k1 logic @128thr).
//   P2: 1536 items = (expert, 8-entry tile); r12's verified wave tile:
//       wave = 4 entries x 8 ranks (acc[32]), 2 waves = 2 rank-halves,
//       2 passes for 8 entries; x prefetch; butterfly; silu -> acts (ws).
//   P3: block = (pair pb=bid&255, chunk=bid>>8 of 8 x 256 cols); bucket+acts
//       staged in LDS; wb cols of both experts in 64 VGPRs; 2 cols/thread;
//       NT stores; out written exactly once. (r7's verified structure.)
// __threadfence() before each grid.sync() for cross-XCD visibility (G16).
// Fallback: if hipLaunchCooperativeKernel is refused, launch the r13
// three-kernel path (same file) -> worst case reproduces r13's 127us.

#define NDIM   2048
#define RANK   16
#define NEXP   16
#define TOKENS 4096
#define CAP_E  768
#define CAP_P  64
#define BLOCK  128
#define GRID   2048
#define P2_ITEMS (NEXP * (CAP_E / 8))   // 1536

#define DOT4(a, b) ((a).x*(b).x + (a).y*(b).y + (a).z*(b).z + (a).w*(b).w)

__global__ __launch_bounds__(BLOCK, 4) void moe_coop(
    const float* __restrict__ x, const float* __restrict__ routing,
    const int* __restrict__ idxs, const float* __restrict__ wa,
    const float* __restrict__ wb, float* __restrict__ out,
    int* __restrict__ cntE, int* __restrict__ cntP,
    int* __restrict__ bucketE, int* __restrict__ bucketP,
    float* __restrict__ acts)
{
    const int bid  = blockIdx.x;
    const int tid  = threadIdx.x;
    const int lane = tid & 63;
    const int wave = tid >> 6;                  // 0..1
    cg::grid_group grid = cg::this_grid();

    __shared__ int   stok[CAP_P];
    __shared__ float srout[CAP_P][2];
    __shared__ __align__(16) float sacts[CAP_P][2 * RANK];   // 8 KB
    __shared__ int scnt;

    // ================= phase 1: bucketing =================
    if (bid < NEXP + NEXP * NEXP) {
        if (tid == 0) scnt = 0;
        __syncthreads();
        if (bid < NEXP) {                       // expert bucket
            const int e = bid;
            const int4* p4 = (const int4*)idxs;
            int* bk = bucketE + e * CAP_E;
            for (int i = tid; i < TOKENS * 2 / 4; i += BLOCK) {
                int4 v = p4[i];
                if (v.x == e) { int p = atomicAdd(&scnt, 1); if (p < CAP_E) bk[p] = 4*i+0; }
                if (v.y == e) { int p = atomicAdd(&scnt, 1); if (p < CAP_E) bk[p] = 4*i+1; }
                if (v.z == e) { int p = atomicAdd(&scnt, 1); if (p < CAP_E) bk[p] = 4*i+2; }
                if (v.w == e) { int p = atomicAdd(&scnt, 1); if (p < CAP_E) bk[p] = 4*i+3; }
            }
            __syncthreads();
            if (tid == 0) cntE[e] = scnt < CAP_E ? scnt : CAP_E;
        } else {                                // pair bucket
            const int pb = bid - NEXP;
            const int e0 = pb >> 4, e1 = pb & (NEXP - 1);
            const int2* p2 = (const int2*)idxs;
            int* bk = bucketP + pb * CAP_P;
            for (int t = tid; t < TOKENS; t += BLOCK) {
                int2 v = p2[t];
                if (v.x == e0 && v.y == e1) {
                    int p = atomicAdd(&scnt, 1);
                    if (p < CAP_P) bk[p] = t;
                }
            }
            __syncthreads();
            if (tid == 0) cntP[pb] = scnt < CAP_P ? scnt : CAP_P;
        }
    }
    __threadfence();
    grid.sync();

    // ================= phase 2: stage A =================
    if (bid < P2_ITEMS) {
        const int e     = bid & (NEXP - 1);
        const int tile2 = bid >> 4;             // 0..95
        int n = cntE[e];
        const int start = tile2 * 8;
        int m2 = n - start;
        if (m2 > 0) {
            if (m2 > 8) m2 = 8;
            if (tid < 8) {
                int src = tid < m2 ? tid : m2 - 1;   // duplicate last in short tiles
                stok[tid] = bucketE[e * CAP_E + start + src];
            }
            __syncthreads();
            const float* wbase = wa + ((size_t)e * RANK + wave * 8) * NDIM + lane * 4;

            #pragma unroll
            for (int pass = 0; pass < 2; pass++) {   // entries pass*4 .. +3
                const float* xp[4];
                #pragma unroll
                for (int j = 0; j < 4; j++)
                    xp[j] = x + (size_t)(stok[pass * 4 + j] >> 1) * NDIM + lane * 4;

                float acc[32];                       // [entry 0..3][rank 0..7]
                #pragma unroll
                for (int i = 0; i < 32; i++) acc[i] = 0.f;

                float4 xc[4], xn[4];
                #pragma unroll
                for (int j = 0; j < 4; j++) xc[j] = *(const float4*)(xp[j]);

                for (int s = 0; s < NDIM / 256; s++) {
                    if (s < NDIM / 256 - 1) {
                        #pragma unroll
                        for (int j = 0; j < 4; j++)
                            xn[j] = *(const float4*)(xp[j] + (s + 1) * 256);
                    }
                    const float* wstep = wbase + s * 256;
                    float4 wv[8];
                    #pragma unroll
                    for (int r = 0; r < 8; r++)
                        wv[r] = *(const float4*)(wstep + r * NDIM);
                    #pragma unroll
                    for (int r = 0; r < 8; r++) {
                        acc[r]      += DOT4(xc[0], wv[r]);
                        acc[8 + r]  += DOT4(xc[1], wv[r]);
                        acc[16 + r] += DOT4(xc[2], wv[r]);
                        acc[24 + r] += DOT4(xc[3], wv[r]);
                    }
                    #pragma unroll
                    for (int j = 0; j < 4; j++) xc[j] = xn[j];
                }

                // reduce 32 values over 64 lanes (r12-verified)
                #pragma unroll
                for (int i = 0; i < 32; i++) acc[i] += __shfl_xor(acc[i], 32, 64);
                #pragma unroll
                for (int mw = 16; mw >= 1; mw >>= 1) {
                    const bool up = (lane & mw) != 0;
                    #pragma unroll
                    for (int i = 0; i < mw; i++) {
                        float lo = acc[i], hi = acc[i + mw];
                        float mine = up ? hi : lo;
                        float give = up ? lo : hi;
                        acc[i] = mine + __shfl_xor(give, mw, 64);
                    }
                }
                if (lane < 32) {
                    float v  = acc[0];
                    float sv = v / (1.f + __expf(-v));   // silu
                    int ent  = stok[pass * 4 + (lane >> 3)];
                    int rank = wave * 8 + (lane & 7);
                    acts[(size_t)ent * RANK + rank] = sv;
                }
            }
        }
    }
    __threadfence();
    grid.sync();

    // ================= phase 3: stage B =================
    {
        const int pb    = bid & 255;
        const int chunk = bid >> 8;             // 0..7 (256 cols each)
        int m = cntP[pb];
        if (m > 0) {
            if (m > CAP_P) m = CAP_P;
            const int e0 = pb >> 4, e1 = pb & (NEXP - 1);
            const int* bp = bucketP + pb * CAP_P;
            if (tid < m) {
                int t = bp[tid];
                stok[tid] = t;
                srout[tid][0] = routing[2 * t];
                srout[tid][1] = routing[2 * t + 1];
            }
            __syncthreads();
            for (int idx = tid; idx < m * 8; idx += BLOCK) {
                int tok = idx >> 3, q = idx & 7;
                float4 v = *(const float4*)(acts + (size_t)stok[tok] * 2 * RANK + q * 4);
                *(float4*)&sacts[tok][q * 4] = v;
            }
            __syncthreads();

            const int d0 = chunk * 256 + tid;
            const int d1 = d0 + 128;
            const float4* p00 = (const float4*)(wb + ((size_t)e0 * NDIM + d0) * RANK);
            const float4* p01 = (const float4*)(wb + ((size_t)e0 * NDIM + d1) * RANK);
            const float4* p10 = (const float4*)(wb + ((size_t)e1 * NDIM + d0) * RANK);
            const float4* p11 = (const float4*)(wb + ((size_t)e1 * NDIM + d1) * RANK);
            const float4 a00 = p00[0], a01 = p00[1], a02 = p00[2], a03 = p00[3];
            const float4 b00 = p01[0], b01 = p01[1], b02 = p01[2], b03 = p01[3];
            const float4 a10 = p10[0], a11 = p10[1], a12 = p10[2], a13 = p10[3];
            const float4 b10 = p11[0], b11 = p11[1], b12 = p11[2], b13 = p11[3];

            #pragma unroll 2
            for (int i = 0; i < m; i++) {
                const float4* a = (const float4*)sacts[i];
                float4 A0 = a[0], A1 = a[1], A2 = a[2], A3 = a[3];
                float4 B0 = a[4], B1 = a[5], B2 = a[6], B3 = a[7];
                float s0_0 = DOT4(a00, A0) + DOT4(a01, A1) + DOT4(a02, A2) + DOT4(a03, A3);
                float s1_0 = DOT4(a10, B0) + DOT4(a11, B1) + DOT4(a12, B2) + DOT4(a13, B3);
                float s0_1 = DOT4(b00, A0) + DOT4(b01, A1) + DOT4(b02, A2) + DOT4(b03, A3);
                float s1_1 = DOT4(b10, B0) + DOT4(b11, B1) + DOT4(b12, B2) + DOT4(b13, B3);
                const float r0 = srout[i][0], r1 = srout[i][1];
                float* op = out + (size_t)stok[i] * NDIM;
                __builtin_nontemporal_store(2.0f * (r0 * s0_0 + r1 * s1_0), op + d0);
                __builtin_nontemporal_store(2.0f * (r0 * s0_1 + r1 * s1_1), op + d1);
            }
        }
    }
}

// ================= fallback: r13 three-kernel path =================
__global__ __launch_bounds__(256) void k1_bucket(const int* __restrict__ idxs,
                                                 int* __restrict__ cntE,
                                                 int* __restrict__ cntP,
                                                 int* __restrict__ bucketE,
                                                 int* __restrict__ bucketP) {
    __shared__ int lcnt;
    const int bid = blockIdx.x;
    const int tid = threadIdx.x;
    if (tid == 0) lcnt = 0;
    __syncthreads();
    if (bid < NEXP) {
        const int e = bid;
        const int4* p4 = (const int4*)idxs;
        int* bk = bucketE + e * CAP_E;
        for (int i = tid; i < TOKENS * 2 / 4; i += 256) {
            int4 v = p4[i];
            if (v.x == e) { int p = atomicAdd(&lcnt, 1); if (p < CAP_E) bk[p] = 4*i+0; }
            if (v.y == e) { int p = atomicAdd(&lcnt, 1); if (p < CAP_E) bk[p] = 4*i+1; }
            if (v.z == e) { int p = atomicAdd(&lcnt, 1); if (p < CAP_E) bk[p] = 4*i+2; }
            if (v.w == e) { int p = atomicAdd(&lcnt, 1); if (p < CAP_E) bk[p] = 4*i+3; }
        }
        __syncthreads();
        if (tid == 0) cntE[e] = lcnt < CAP_E ? lcnt : CAP_E;
    } else {
        const int pb = bid - NEXP;
        const int e0 = pb >> 4, e1 = pb & (NEXP - 1);
        const int2* p2 = (const int2*)idxs;
        int* bk = bucketP + pb * CAP_P;
        for (int t = tid; t < TOKENS; t += 256) {
            int2 v = p2[t];
            if (v.x == e0 && v.y == e1) {
                int p = atomicAdd(&lcnt, 1);
                if (p < CAP_P) bk[p] = t;
            }
        }
        __syncthreads();
        if (tid == 0) cntP[pb] = lcnt < CAP_P ? lcnt : CAP_P;
    }
}

__global__ __launch_bounds__(256, 4) void k2_stage_a(const float* __restrict__ x,
                                                     const float* __restrict__ wa,
                                                     const int* __restrict__ cntE,
                                                     const int* __restrict__ bucketE,
                                                     float* __restrict__ acts) {
    const int e    = blockIdx.x & (NEXP - 1);
    const int tile = blockIdx.x >> 4;
    int n = cntE[e];
    const int start = tile * 8;
    int m = n - start;
    if (m <= 0) return;
    if (m > 8) m = 8;
    __shared__ int sTok[8];
    const int tid = threadIdx.x, lane = tid & 63, wave = tid >> 6;
    const int entgrp = wave & 1, rhalf = wave >> 1;
    if (tid < 8) {
        int src = tid < m ? tid : m - 1;
        sTok[tid] = bucketE[e * CAP_E + start + src];
    }
    __syncthreads();
    const float* xp[4];
    #pragma unroll
    for (int j = 0; j < 4; j++)
        xp[j] = x + (size_t)(sTok[entgrp * 4 + j] >> 1) * NDIM + lane * 4;
    const float* wbase = wa + ((size_t)e * RANK + rhalf * 8) * NDIM + lane * 4;
    float acc[32];
    #pragma unroll
    for (int i = 0; i < 32; i++) acc[i] = 0.f;
    float4 xc[4], xn[4];
    #pragma unroll
    for (int j = 0; j < 4; j++) xc[j] = *(const float4*)(xp[j]);
    for (int s = 0; s < NDIM / 256; s++) {
        if (s < NDIM / 256 - 1) {
            #pragma unroll
            for (int j = 0; j < 4; j++) xn[j] = *(const float4*)(xp[j] + (s + 1) * 256);
        }
        const float* wstep = wbase + s * 256;
        float4 wv[8];
        #pragma unroll
        for (int r = 0; r < 8; r++) wv[r] = *(const float4*)(wstep + r * NDIM);
        #pragma unroll
        for (int r = 0; r < 8; r++) {
            acc[r]      += DOT4(xc[0], wv[r]);
            acc[8 + r]  += DOT4(xc[1], wv[r]);
            acc[16 + r] += DOT4(xc[2], wv[r]);
            acc[24 + r] += DOT4(xc[3], wv[r]);
        }
        #pragma unroll
        for (int j = 0; j < 4; j++) xc[j] = xn[j];
    }
    #pragma unroll
    for (int i = 0; i < 32; i++) acc[i] += __shfl_xor(acc[i], 32, 64);
    #pragma unroll
    for (int mw = 16; mw >= 1; mw >>= 1) {
        const bool up = (lane & mw) != 0;
        #pragma unroll
        for (int i = 0; i < mw; i++) {
            float lo = acc[i], hi = acc[i + mw];
            float mine = up ? hi : lo;
            float give = up ? lo : hi;
            acc[i] = mine + __shfl_xor(give, mw, 64);
        }
    }
    if (lane < 32) {
        float v  = acc[0];
        float sv = v / (1.f + __expf(-v));
        int ent  = sTok[entgrp * 4 + (lane >> 3)];
        int rank = rhalf * 8 + (lane & 7);
        acts[(size_t)ent * RANK + rank] = sv;
    }
}

__global__ __launch_bounds__(256, 2) void k3_stage_b(const float* __restrict__ routing,
                                                     const float* __restrict__ wb,
                                                     const int* __restrict__ cntP,
                                                     const int* __restrict__ bucketP,
                                                     const float* __restrict__ acts,
                                                     float* __restrict__ out) {
    const int pb  = blockIdx.x & (NEXP * NEXP - 1);
    const int dch = blockIdx.x >> 8;
    int m = cntP[pb];
    if (m <= 0) return;
    if (m > CAP_P) m = CAP_P;
    const int e0 = pb >> 4, e1 = pb & (NEXP - 1);
    const int tid = threadIdx.x;
    const int d0 = dch * 512 + tid;
    const int d1 = d0 + 256;
    __shared__ float sacts[CAP_P][2 * RANK];
    __shared__ float srout[CAP_P][2];
    __shared__ int   stok[CAP_P];
    const int* bp = bucketP + pb * CAP_P;
    if (tid < m) {
        int t = bp[tid];
        stok[tid] = t;
        srout[tid][0] = routing[2 * t];
        srout[tid][1] = routing[2 * t + 1];
    }
    __syncthreads();
    for (int idx = tid; idx < m * 8; idx += 256) {
        int tok = idx >> 3, q = idx & 7;
        float4 v = *(const float4*)(acts + (size_t)stok[tok] * 2 * RANK + q * 4);
        *(float4*)&sacts[tok][q * 4] = v;
    }
    __syncthreads();
    const float4* p00 = (const float4*)(wb + ((size_t)e0 * NDIM + d0) * RANK);
    const float4* p01 = (const float4*)(wb + ((size_t)e0 * NDIM + d1) * RANK);
    const float4* p10 = (const float4*)(wb + ((size_t)e1 * NDIM + d0) * RANK);
    const float4* p11 = (const float4*)(wb + ((size_t)e1 * NDIM + d1) * RANK);
    const float4 a00 = p00[0], a01 = p00[1], a02 = p00[2], a03 = p00[3];
    const float4 b00 = p01[0], b01 = p01[1], b02 = p01[2], b03 = p01[3];
    const float4 a10 = p10[0], a11 = p10[1], a12 = p10[2], a13 = p10[3];
    const float4 b10 = p11[0], b11 = p11[1], b12 = p11[2], b13 = p11[3];
    #pragma unroll 2
    for (int i = 0; i < m; i++) {
        const float4* a = (const float4*)sacts[i];
        float4 A0 = a[0], A1 = a[1], A2 = a[2], A3 = a[3];
        float4 B0 = a[4], B1 = a[5], B2 = a[6], B3 = a[7];
        float s0_0 = DOT4(a00, A0) + DOT4(a01, A1) + DOT4(a02, A2) + DOT4(a03, A3);
        float s1_0 = DOT4(a10, B0) + DOT4(a11, B1) + DOT4(a12, B2) + DOT4(a13, B3);
        float s0_1 = DOT4(b00, A0) + DOT4(b01, A1) + DOT4(b02, A2) + DOT4(b03, A3);
        float s1_1 = DOT4(b10, B0) + DOT4(b11, B1) + DOT4(b12, B2) + DOT4(b13, B3);
        const float r0 = srout[i][0], r1 = srout[i][1];
        float* op = out + (size_t)stok[i] * NDIM;
        __builtin_nontemporal_store(2.0f * (r0 * s0_0 + r1 * s1_0), op + d0);
        __builtin_nontemporal_store(2.0f * (r0 * s0_1 + r1 * s1_1), op + d1);
    }
}

extern "C" void kernel_launch(void* const* d_in, const int* in_sizes, int n_in,
                              void* d_out, int out_size, void* d_ws, size_t ws_size,
                              hipStream_t stream) {
    const float* x       = (const float*)d_in[0];
    const float* routing = (const float*)d_in[1];
    const int*   idxs    = (const int*)  d_in[2];
    const float* wa      = (const float*)d_in[3];
    const float* wb      = (const float*)d_in[4];
    float*       out     = (float*)d_out;

    int*   cntE    = (int*)d_ws;
    int*   cntP    = (int*)((char*)d_ws + 64);
    int*   bucketE = (int*)((char*)d_ws + 2048);
    int*   bucketP = (int*)((char*)d_ws + 2048 + NEXP * CAP_E * 4);
    float* acts    = (float*)((char*)d_ws + 2048 + NEXP * CAP_E * 4
                                          + NEXP * NEXP * CAP_P * 4);

    void* args[] = { (void*)&x, (void*)&routing, (void*)&idxs, (void*)&wa,
                     (void*)&wb, (void*)&out, (void*)&cntE, (void*)&cntP,
                     (void*)&bucketE, (void*)&bucketP, (void*)&acts };
    hipError_t err = hipLaunchCooperativeKernel((const void*)moe_coop,
                                                dim3(GRID), dim3(BLOCK),
                                                args, 0, stream);
    if (err != hipSuccess) {
        // fallback: r13 three-kernel path
        k1_bucket <<<NEXP + NEXP * NEXP, 256, 0, stream>>>(idxs, cntE, cntP,
                                                           bucketE, bucketP);
        k2_stage_a<<<NEXP * (CAP_E / 8), 256, 0, stream>>>(x, wa, cntE, bucketE, acts);
        k3_stage_b<<<NEXP * NEXP * (NDIM / 512), 256, 0, stream>>>(routing, wb, cntP,
                                                                   bucketP, acts, out);
    }
}

// Round 15
// 131.859 us; speedup vs baseline: 6.8230x; 6.8230x over previous
//
#include <hip/hip_runtime.h>

// SparseLoRAMoE, expert-grouped, atomic-free. Round-15: stage A on MFMA.
// Session ledger: six fp32-VALU stage-A designs all pinned at ~40us (6x the
// 6.8us VALU floor). Cause chain (measured): acc>=32 fp32 -> >64 VGPR -> max
// 4 waves/SIMD (m69 occupancy steps), and the compiler refuses to hoist
// global loads regardless of register budget (r11: VGPR=104 under 256 cap).
// r14's cooperative probe confirmed the spill cliff (194MB scratch writes).
// Fix: bf16x2-split MFMA. Per expert: [tok x 2048] . [2048 x 16] via
// 3x mfma_f32_16x16x32_bf16 (xh.wh + xl.wh + xh.wl) into ONE fp32 acc.
//   - products exact in fp32 accum; dropped xl.wl ~2^-18 rel -> absmax ~same
//   - k-slot mapping uncertainty cancels: A and B use the SAME k permutation
//   - C/D mapping (HW-verified): col=lane&15, row=(lane>>4)*4+reg
//   - acc 4 + frags 16 regs -> ~60 VGPR: no spill possible, MFMA pipe (idle
//     all session, MfmaUtil=0.0) does the work
//   K0 (512 blocks): split wa -> wah/wal bf16 in workspace (8MB R, 4MB W)
//   K1 (272 blocks): bucketing (unchanged)
//   K2 (768 blocks x 256): block = (expert, 16-entry tile); wave w owns
//       K-quarter [w*512,(w+1)*512): 16 K-tiles x {2 x-loads, on-fly split,
//       2 bf16x8 B-loads, 3 MFMA}; partials -> LDS; combine+silu -> acts
//   K3 (1024 blocks): 2 cols/thread, LDS bucket, NT stores (unchanged)
// No zeroing, no atomics on out, bit-deterministic.

#define NDIM   2048
#define RANK   16
#define NEXP   16
#define TOKENS 4096
#define CAP_E  768
#define CAP_P  64
#define TILE_E 16
#define ETILES (CAP_E / TILE_E)   // 48

#define DOT4(a, b) ((a).x*(b).x + (a).y*(b).y + (a).z*(b).z + (a).w*(b).w)

typedef short  bf16x8 __attribute__((ext_vector_type(8)));
typedef float  f32x4  __attribute__((ext_vector_type(4)));

__device__ __forceinline__ unsigned short f2bf(float f) {   // RTN bf16
    unsigned int u = __float_as_uint(f);
    u += 0x7FFFu + ((u >> 16) & 1u);
    return (unsigned short)(u >> 16);
}

// ---------------- K0: split wa into bf16 hi/lo ----------------
__global__ __launch_bounds__(256) void k0_conv(const float* __restrict__ wa,
                                               unsigned short* __restrict__ wah,
                                               unsigned short* __restrict__ wal) {
    const int i = blockIdx.x * 256 + threadIdx.x;     // float4 index
    if (i >= NEXP * RANK * NDIM / 4) return;
    float4 v = ((const float4*)wa)[i];
    ushort4 h, l;
    h.x = f2bf(v.x); l.x = f2bf(v.x - __uint_as_float((unsigned)h.x << 16));
    h.y = f2bf(v.y); l.y = f2bf(v.y - __uint_as_float((unsigned)h.y << 16));
    h.z = f2bf(v.z); l.z = f2bf(v.z - __uint_as_float((unsigned)h.z << 16));
    h.w = f2bf(v.w); l.w = f2bf(v.w - __uint_as_float((unsigned)h.w << 16));
    ((ushort4*)wah)[i] = h;
    ((ushort4*)wal)[i] = l;
}

// ---------------- K1: bucketing, one block per bucket ----------------
__global__ __launch_bounds__(256) void k1_bucket(const int* __restrict__ idxs,
                                                 int* __restrict__ cntE,
                                                 int* __restrict__ cntP,
                                                 int* __restrict__ bucketE,
                                                 int* __restrict__ bucketP) {
    __shared__ int lcnt;
    const int bid = blockIdx.x;
    const int tid = threadIdx.x;
    if (tid == 0) lcnt = 0;
    __syncthreads();
    if (bid < NEXP) {
        const int e = bid;
        const int4* p4 = (const int4*)idxs;
        int* bk = bucketE + e * CAP_E;
        for (int i = tid; i < TOKENS * 2 / 4; i += 256) {
            int4 v = p4[i];
            if (v.x == e) { int p = atomicAdd(&lcnt, 1); if (p < CAP_E) bk[p] = 4*i+0; }
            if (v.y == e) { int p = atomicAdd(&lcnt, 1); if (p < CAP_E) bk[p] = 4*i+1; }
            if (v.z == e) { int p = atomicAdd(&lcnt, 1); if (p < CAP_E) bk[p] = 4*i+2; }
            if (v.w == e) { int p = atomicAdd(&lcnt, 1); if (p < CAP_E) bk[p] = 4*i+3; }
        }
        __syncthreads();
        if (tid == 0) cntE[e] = lcnt < CAP_E ? lcnt : CAP_E;
    } else {
        const int pb = bid - NEXP;
        const int e0 = pb >> 4, e1 = pb & (NEXP - 1);
        const int2* p2 = (const int2*)idxs;
        int* bk = bucketP + pb * CAP_P;
        for (int t = tid; t < TOKENS; t += 256) {
            int2 v = p2[t];
            if (v.x == e0 && v.y == e1) {
                int p = atomicAdd(&lcnt, 1);
                if (p < CAP_P) bk[p] = t;
            }
        }
        __syncthreads();
        if (tid == 0) cntP[pb] = lcnt < CAP_P ? lcnt : CAP_P;
    }
}

// ---------------- K2: stage A via bf16x2-split MFMA ----------------
__global__ __launch_bounds__(256, 4) void k2_mfma(const float* __restrict__ x,
                                                  const unsigned short* __restrict__ wah,
                                                  const unsigned short* __restrict__ wal,
                                                  const int* __restrict__ cntE,
                                                  const int* __restrict__ bucketE,
                                                  float* __restrict__ acts) {
    const int e    = blockIdx.x & (NEXP - 1);
    const int tile = blockIdx.x >> 4;           // 0..ETILES-1
    int n = cntE[e];
    const int start = tile * TILE_E;
    int m = n - start;
    if (m <= 0) return;
    if (m > TILE_E) m = TILE_E;

    __shared__ int   sTok[TILE_E];
    __shared__ float part[4][TILE_E][RANK];     // 4 KB of K-quarter partials

    const int tid  = threadIdx.x;
    const int lane = tid & 63;
    const int w    = tid >> 6;                  // K-quarter 0..3
    const int row  = lane & 15;                 // A: token idx / B: rank
    const int g    = lane >> 4;                 // k-group 0..3

    if (tid < TILE_E) {
        int src = tid < m ? tid : m - 1;        // duplicate last in short tiles
        sTok[tid] = bucketE[e * CAP_E + start + src];
    }
    __syncthreads();

    const float*          xrow = x   + (size_t)(sTok[row] >> 1) * NDIM;
    const unsigned short* bhp  = wah + ((size_t)e * RANK + row) * NDIM;
    const unsigned short* blp  = wal + ((size_t)e * RANK + row) * NDIM;

    f32x4 acc = {0.f, 0.f, 0.f, 0.f};

    for (int kt = w * 16; kt < w * 16 + 16; kt++) {     // 16 K-tiles of 32
        const int kb = kt * 32 + g * 8;                 // shared k-permutation
        float4 xa = *(const float4*)(xrow + kb);
        float4 xb = *(const float4*)(xrow + kb + 4);
        // on-the-fly bf16 split of the A fragment
        bf16x8 Ah, Al;
        float xs0 = xa.x, xs1 = xa.y, xs2 = xa.z, xs3 = xa.w;
        float xs4 = xb.x, xs5 = xb.y, xs6 = xb.z, xs7 = xb.w;
        unsigned short h0 = f2bf(xs0), h1 = f2bf(xs1), h2 = f2bf(xs2), h3 = f2bf(xs3);
        unsigned short h4 = f2bf(xs4), h5 = f2bf(xs5), h6 = f2bf(xs6), h7 = f2bf(xs7);
        Ah[0] = (short)h0; Ah[1] = (short)h1; Ah[2] = (short)h2; Ah[3] = (short)h3;
        Ah[4] = (short)h4; Ah[5] = (short)h5; Ah[6] = (short)h6; Ah[7] = (short)h7;
        Al[0] = (short)f2bf(xs0 - __uint_as_float((unsigned)h0 << 16));
        Al[1] = (short)f2bf(xs1 - __uint_as_float((unsigned)h1 << 16));
        Al[2] = (short)f2bf(xs2 - __uint_as_float((unsigned)h2 << 16));
        Al[3] = (short)f2bf(xs3 - __uint_as_float((unsigned)h3 << 16));
        Al[4] = (short)f2bf(xs4 - __uint_as_float((unsigned)h4 << 16));
        Al[5] = (short)f2bf(xs5 - __uint_as_float((unsigned)h5 << 16));
        Al[6] = (short)f2bf(xs6 - __uint_as_float((unsigned)h6 << 16));
        Al[7] = (short)f2bf(xs7 - __uint_as_float((unsigned)h7 << 16));

        bf16x8 Bh = *(const bf16x8*)(bhp + kb);         // pre-split wa (16B)
        bf16x8 Bl = *(const bf16x8*)(blp + kb);

        acc = __builtin_amdgcn_mfma_f32_16x16x32_bf16(Ah, Bh, acc, 0, 0, 0);
        acc = __builtin_amdgcn_mfma_f32_16x16x32_bf16(Al, Bh, acc, 0, 0, 0);
        acc = __builtin_amdgcn_mfma_f32_16x16x32_bf16(Ah, Bl, acc, 0, 0, 0);
    }

    // D layout (verified): col=lane&15 (=rank), row=(lane>>4)*4+reg (=token)
    #pragma unroll
    for (int q = 0; q < 4; q++)
        part[w][g * 4 + q][row] = acc[q];
    __syncthreads();

    {   // combine K-quarters + silu + store
        const int tok = tid >> 4;               // 0..15
        const int rk  = tid & 15;
        float v = (part[0][tok][rk] + part[1][tok][rk])
                + (part[2][tok][rk] + part[3][tok][rk]);
        float sv = v / (1.f + __expf(-v));      // silu
        acts[(size_t)sTok[tok] * RANK + rk] = sv;   // dup entries: same value
    }
}

// ---------------- K3: stage B, 2 cols/thread, LDS bucket, NT stores ----------------
__global__ __launch_bounds__(256, 2) void k3_stage_b(const float* __restrict__ routing,
                                                     const float* __restrict__ wb,
                                                     const int* __restrict__ cntP,
                                                     const int* __restrict__ bucketP,
                                                     const float* __restrict__ acts,
                                                     float* __restrict__ out) {
    const int pb  = blockIdx.x & (NEXP * NEXP - 1);
    const int dch = blockIdx.x >> 8;            // 0..3 (512 cols per block)
    int m = cntP[pb];
    if (m <= 0) return;
    if (m > CAP_P) m = CAP_P;
    const int e0 = pb >> 4;
    const int e1 = pb & (NEXP - 1);
    const int tid = threadIdx.x;
    const int d0 = dch * 512 + tid;
    const int d1 = d0 + 256;

    __shared__ float sacts[CAP_P][2 * RANK];
    __shared__ float srout[CAP_P][2];
    __shared__ int   stok[CAP_P];

    const int* bp = bucketP + pb * CAP_P;
    if (tid < m) {
        int t = bp[tid];
        stok[tid] = t;
        srout[tid][0] = routing[2 * t];
        srout[tid][1] = routing[2 * t + 1];
    }
    __syncthreads();
    for (int idx = tid; idx < m * 8; idx += 256) {
        int tok = idx >> 3, q = idx & 7;
        float4 v = *(const float4*)(acts + (size_t)stok[tok] * 2 * RANK + q * 4);
        *(float4*)&sacts[tok][q * 4] = v;
    }
    __syncthreads();

    const float4* p00 = (const float4*)(wb + ((size_t)e0 * NDIM + d0) * RANK);
    const float4* p01 = (const float4*)(wb + ((size_t)e0 * NDIM + d1) * RANK);
    const float4* p10 = (const float4*)(wb + ((size_t)e1 * NDIM + d0) * RANK);
    const float4* p11 = (const float4*)(wb + ((size_t)e1 * NDIM + d1) * RANK);
    const float4 a00 = p00[0], a01 = p00[1], a02 = p00[2], a03 = p00[3];
    const float4 b00 = p01[0], b01 = p01[1], b02 = p01[2], b03 = p01[3];
    const float4 a10 = p10[0], a11 = p10[1], a12 = p10[2], a13 = p10[3];
    const float4 b10 = p11[0], b11 = p11[1], b12 = p11[2], b13 = p11[3];

    #pragma unroll 2
    for (int i = 0; i < m; i++) {
        const float4* a = (const float4*)sacts[i];
        float4 A0 = a[0], A1 = a[1], A2 = a[2], A3 = a[3];
        float4 B0 = a[4], B1 = a[5], B2 = a[6], B3 = a[7];
        float s0_0 = DOT4(a00, A0) + DOT4(a01, A1) + DOT4(a02, A2) + DOT4(a03, A3);
        float s1_0 = DOT4(a10, B0) + DOT4(a11, B1) + DOT4(a12, B2) + DOT4(a13, B3);
        float s0_1 = DOT4(b00, A0) + DOT4(b01, A1) + DOT4(b02, A2) + DOT4(b03, A3);
        float s1_1 = DOT4(b10, B0) + DOT4(b11, B1) + DOT4(b12, B2) + DOT4(b13, B3);
        const float r0 = srout[i][0], r1 = srout[i][1];
        float* op = out + (size_t)stok[i] * NDIM;
        __builtin_nontemporal_store(2.0f * (r0 * s0_0 + r1 * s1_0), op + d0);
        __builtin_nontemporal_store(2.0f * (r0 * s0_1 + r1 * s1_1), op + d1);
    }
}

extern "C" void kernel_launch(void* const* d_in, const int* in_sizes, int n_in,
                              void* d_out, int out_size, void* d_ws, size_t ws_size,
                              hipStream_t stream) {
    const float* x       = (const float*)d_in[0];
    const float* routing = (const float*)d_in[1];
    const int*   idxs    = (const int*)  d_in[2];
    const float* wa      = (const float*)d_in[3];
    const float* wb      = (const float*)d_in[4];
    float*       out     = (float*)d_out;

    // ws layout (bytes): [cntE 64][cntP @64][bucketE @2048 48KB]
    // [bucketP @51200 64KB][acts @116736 512KB][wah @641024 1MB][wal @1689600 1MB]
    int*            cntE    = (int*)d_ws;
    int*            cntP    = (int*)((char*)d_ws + 64);
    int*            bucketE = (int*)((char*)d_ws + 2048);
    int*            bucketP = (int*)((char*)d_ws + 2048 + NEXP * CAP_E * 4);
    float*          acts    = (float*)((char*)d_ws + 116736);
    unsigned short* wah     = (unsigned short*)((char*)d_ws + 641024);
    unsigned short* wal     = (unsigned short*)((char*)d_ws + 1689600);

    k0_conv  <<<NEXP * RANK * NDIM / 4 / 256, 256, 0, stream>>>(wa, wah, wal);
    k1_bucket<<<NEXP + NEXP * NEXP, 256, 0, stream>>>(idxs, cntE, cntP, bucketE, bucketP);
    k2_mfma  <<<NEXP * ETILES, 256, 0, stream>>>(x, wah, wal, cntE, bucketE, acts);
    k3_stage_b<<<NEXP * NEXP * (NDIM / 512), 256, 0, stream>>>(routing, wb, cntP,
                                                               bucketP, acts, out);
}